// Round 18
// baseline (3150.454 us; speedup 1.0000x reference)
//
#include <hip/hip_runtime.h>
#include <math.h>

#define NT   64
#define NB   16
#define OUTS 256
#define WL   128
#define NC   256
#define NR   4
#define HIDN 512
#define G4   2048
#define KTOT 1280
#define WCH  391
#define COUT 927
#define EPSF 1e-6f
#define NBLK 256
#define THR  1024

// LDS float offsets (weight rows padded off power-of-2 strides)
#define O_WG    0        // 10272: gates W [c][1284]
#define O_WCc   10272    // 2064 : ctrl W [cl][516]
#define O_WOc   12336    // 1024 : out W [k2]
#define O_PRD   13360    // 1024
#define O_USG   14384    // 256
#define O_PRC   14640    // 256
#define O_WDP   14896    // 256
#define O_COWN  15152    // 32
#define O_RED   15184    // 2560
#define O_SCAL  17744    // 32
#define O_SCT   17776    // 16
#define O_UNI   17792    // 20544 union: act[16][1284] | C/D/E scratch
#define SH_FLOATS 38336  // 153,344 B

__device__ __forceinline__ float sigf(float x){ return 1.0f/(1.0f+expf(-x)); }
__device__ __forceinline__ float oneplusf(float x){ return fmaxf(x,0.0f)+log1pf(expf(-fabsf(x)))+1.0f; }

__device__ __forceinline__ float waveSum(float v){
#pragma unroll
  for(int o=32;o>0;o>>=1) v += __shfl_down(v,o,64);
  return v;
}
__device__ __forceinline__ float waveMax(float v){
#pragma unroll
  for(int o=32;o>0;o>>=1) v = fmaxf(v,__shfl_down(v,o,64));
  return v;
}

__device__ __forceinline__ void g_storef(float* p, float v){
  __hip_atomic_store(p, v, __ATOMIC_RELAXED, __HIP_MEMORY_SCOPE_AGENT);
}
__device__ __forceinline__ float2 g_loadf2(const float* p){
  unsigned long long v = __hip_atomic_load((const unsigned long long*)p, __ATOMIC_RELAXED, __HIP_MEMORY_SCOPE_AGENT);
  union{unsigned long long u; float2 f;} c; c.u=v; return c.f;
}

// hierarchical barriers (validated R15/R16)
__device__ __forceinline__ void gbarH(int* bar, int b, int gp){
  __syncthreads();
  if (threadIdx.x == 0){
    asm volatile("s_waitcnt vmcnt(0) lgkmcnt(0)" ::: "memory");
    int prev = __hip_atomic_fetch_add(bar + b*32, 1, __ATOMIC_RELAXED, __HIP_MEMORY_SCOPE_AGENT);
    if (prev == 16*gp - 1){
      int p2 = __hip_atomic_fetch_add(bar + 1536, 1, __ATOMIC_RELAXED, __HIP_MEMORY_SCOPE_AGENT);
      if (p2 == 16*gp - 1)
        __hip_atomic_store(bar + 1568, gp, __ATOMIC_RELAXED, __HIP_MEMORY_SCOPE_AGENT);
    }
    while (__hip_atomic_load(bar + 1568, __ATOMIC_RELAXED, __HIP_MEMORY_SCOPE_AGENT) < gp)
      __builtin_amdgcn_s_sleep(1);
    asm volatile("" ::: "memory");
  }
  __syncthreads();
}
__device__ __forceinline__ void lbar(int* bar, int b, int lp){
  __syncthreads();
  if (threadIdx.x == 0){
    asm volatile("s_waitcnt vmcnt(0) lgkmcnt(0)" ::: "memory");
    int prev = __hip_atomic_fetch_add(bar + 512 + b*32, 1, __ATOMIC_RELAXED, __HIP_MEMORY_SCOPE_AGENT);
    if (prev == 16*lp - 1){
      __hip_atomic_store(bar + 1024 + b*32, lp, __ATOMIC_RELAXED, __HIP_MEMORY_SCOPE_AGENT);
    } else {
      while (__hip_atomic_load(bar + 1024 + b*32, __ATOMIC_RELAXED, __HIP_MEMORY_SCOPE_AGENT) < lp)
        __builtin_amdgcn_s_sleep(1);
    }
    asm volatile("" ::: "memory");
  }
  __syncthreads();
}

__global__ void k_zero(float* p, size_t n){
  size_t i = (size_t)blockIdx.x*blockDim.x + threadIdx.x;
  size_t st = (size_t)gridDim.x*blockDim.x;
  for(; i<n; i+=st) p[i]=0.0f;
}

__global__ __launch_bounds__(THR,1) void k_persist(
    const float* __restrict__ Wx, const float* __restrict__ Wh, const float* __restrict__ b_lstm,
    const float* __restrict__ Wc, const float* __restrict__ bc,
    const float* __restrict__ Wo, const float* __restrict__ bo,
    const float* __restrict__ Wr, const float* __restrict__ br,
    const float* __restrict__ in_data,
    float* mem_g, float* linkT_g, float* racc_rot, float* h_rot, float* ctrl_rot,
    float* dots_g, float* bwd_g, float* facc_g, float* rlog_g,
    float* out_g, int* bar)
{
  extern __shared__ float SH[];
  float* s_wg   = SH + O_WG;
  float* s_wc   = SH + O_WCc;
  float* s_wo   = SH + O_WOc;
  float* s_prd  = SH + O_PRD;
  float* s_usage= SH + O_USG;
  float* s_prec = SH + O_PRC;
  float* s_wdp  = SH + O_WDP;
  float* s_cown = SH + O_COWN;
  float* s_red  = SH + O_RED;
  float* s_scal = SH + O_SCAL;
  float* s_sct  = SH + O_SCT;
  float* s_act  = SH + O_UNI;            // [16][1284]
  float* s_ctrl = SH + O_UNI;
  float* s_psi  = SH + O_UNI + 928;
  float* s_su   = SH + O_UNI + 1184;
  float* s_shift= SH + O_UNI + 1440;
  float* s_er   = SH + O_UNI + 1696;
  float* s_mn   = SH + O_UNI + 1824;
  float* s_preo = SH + O_UNI + 1840;
  float* s_link = SH + O_UNI + 1856;     // 4096
  float* s_mem  = SH + O_UNI + 5952;     // 2048
  float* s_fwd  = SH + O_UNI + 8000;     // 1024
  float* s_bwd  = SH + O_UNI + 9024;     // 1024
  float* s_rkey = SH + O_UNI + 10048;    // 528 aligned read-key copy

  const int tid = threadIdx.x, bk = blockIdx.x;
  const int s = bk & 15, b = bk >> 4;

  // ---- one-time LDS weight loads ----
  for(int i=tid;i<10240;i+=THR){
    int c=i&7, k=i>>3;
    int col=(c>>1)*512 + 2*bk + (c&1);
    s_wg[c*1284+k] = (k<768) ? Wx[(size_t)k*G4+col] : Wh[(size_t)(k-768)*G4+col];
  }
  for(int i=tid;i<2048;i+=THR){
    int cl=i&3, k=i>>2;
    int j=4*bk+cl;
    s_wc[cl*516+k] = (bk<232 && j<COUT) ? Wc[(size_t)k*COUT+j] : 0.f;
  }
  for(int i=tid;i<1024;i+=THR){
    s_wo[i] = (i<512) ? Wr[(size_t)i*OUTS+bk] : Wo[(size_t)(i-512)*OUTS+bk];
  }
  for(int i=tid;i<1024;i+=THR) s_prd[i]=0.f;
  for(int i=tid;i<256;i+=THR){ s_usage[i]=0.f; s_prec[i]=0.f; s_wdp[i]=0.f; }
  if(tid<32) s_cown[tid]=0.f;
  __syncthreads();

  int myrk=0; float allocv=0.f;

  for(int t=0;t<=NT;t++){
    // ============ PHASE A: stage act (float4), gates GEMM, LSTM, out(t-1), zero facc ============
    if(t<NT){
      for(int i=tid;i<1024;i+=THR){
        int bi=i>>6, k4=(i&63)*4;
        float4 v = *(const float4*)(in_data + (size_t)t*4096 + bi*256 + k4);
        *(float4*)&s_act[bi*1284+k4] = v;
      }
    }
    for(int i=tid;i<2048;i+=THR){
      int bi=i>>7, k4=(i&127)*4;
      float4 v = *(const float4*)(racc_rot + (size_t)t*8192 + bi*512 + k4);
      *(float4*)&s_act[bi*1284+256+k4] = v;
    }
    for(int i=tid;i<2048;i+=THR){
      int bi=i>>7, k4=(i&127)*4;
      float4 v = *(const float4*)(h_rot + (size_t)t*8192 + bi*512 + k4);
      *(float4*)&s_act[bi*1284+768+k4] = v;
    }
    if(tid<64) g_storef(facc_g + b*1024 + s*64 + tid, 0.0f);
    __syncthreads();
    if(t<NT){
      int oc=tid&127, q=tid>>7;            // 8 k-splits of 160
      int c=oc>>4, bi=oc&15;
      const float* ap = s_act + bi*1284;
      const float* wp = s_wg + c*1284;
      float4 a4={0,0,0,0};
      int k0=q*160;
#pragma unroll 8
      for(int it=0;it<40;it++){
        int k=k0+it*4;
        float4 a=*(const float4*)(ap+k);
        float4 w=*(const float4*)(wp+k);
        a4.x+=a.x*w.x; a4.y+=a.y*w.y; a4.z+=a.z*w.z; a4.w+=a.w*w.w;
      }
      s_red[q*128+oc]=a4.x+a4.y+a4.z+a4.w;
    }
    if(t>0){
      int bi=tid>>6, q=tid&63;             // 64 lanes x 16 iters covers K=1024
      const float* ap = s_act + bi*1284 + 256;
      float acc=0.f;
#pragma unroll 8
      for(int it=0;it<16;it++){
        int k2=q+it*64;                    // stride-1 per lane, spans [0,1024)
        acc += ap[k2]*s_wo[k2];
      }
      s_red[1024 + bi*64 + q] = acc;
    }
    __syncthreads();
    if(t<NT && tid<32){
      int j2=tid>>4, bi=tid&15;
      float g4[4];
#pragma unroll
      for(int g=0;g<4;g++){
        int c=g*2+j2;
        float v=0.f;
#pragma unroll
        for(int q=0;q<8;q++) v += s_red[q*128+c*16+bi];
        v += b_lstm[g*512 + 2*bk + j2];
        g4[g]=v;
      }
      float cc = sigf(g4[1])*s_cown[j2*16+bi] + sigf(g4[0])*tanhf(g4[2]);
      float hh = sigf(g4[3])*tanhf(cc);
      s_cown[j2*16+bi]=cc;
      g_storef(h_rot + (size_t)(t+1)*8192 + bi*512 + 2*bk + j2, hh);
    }
    if(t>0 && tid>=64 && tid<80){
      int bi=tid-64;
      float acc=bo[bk]+br[bk];
#pragma unroll
      for(int q=0;q<64;q++) acc += s_red[1024+bi*64+q];
      out_g[((size_t)(t-1)*NB+bi)*OUTS + bk] = acc;
    }
    if(t==NT) break;
    gbarH(bar,b,3*t+1);

    // ============ PHASE B: ctrl GEMM ============
    for(int i=tid;i<2048;i+=THR){
      int bi=i>>7, k4=(i&127)*4;
      float4 v = *(const float4*)(h_rot + (size_t)(t+1)*8192 + bi*512 + k4);
      *(float4*)&s_act[bi*1284+768+k4] = v;
    }
    __syncthreads();
    if(bk<232){
      int o=tid&63, ks=tid>>6;             // 16 k-splits of 32
      int cl=o>>4, bi=o&15;
      int j=4*bk+cl;
      float acc=0.f;
      if(j<COUT){
        const float* ap=s_act+bi*1284+768;
        const float* wp=s_wc+cl*516;
#pragma unroll
        for(int kk=0;kk<8;kk++){
          int k=ks*32+kk*4;
          float4 a=*(const float4*)(ap+k);
          float4 w=*(const float4*)(wp+k);
          acc += a.x*w.x+a.y*w.y+a.z*w.z+a.w*w.w;
        }
      }
      s_red[ks*64+o]=acc;
    }
    __syncthreads();
    if(bk<232 && tid<64){
      int cl=tid>>4, bi=tid&15; int j=4*bk+cl;
      if(j<COUT){
        float a=bc[j];
#pragma unroll
        for(int ks=0;ks<16;ks++) a+=s_red[ks*64+tid];
        g_storef(ctrl_rot + (size_t)t*14848 + bi*928 + j, fminf(fmaxf(a,-20.f),20.f));
      }
    }
    gbarH(bar,b,3*t+2);

    // ============ PHASE C: psi/usage/alloc + write-key dots ============
    for(int i=tid;i<232;i+=THR){
      float4 v = *(const float4*)(ctrl_rot + (size_t)t*14848 + b*928 + 4*i);
      *(float4*)&s_ctrl[4*i] = v;
    }
    __syncthreads();
    for(int i=tid;i<528;i+=THR) s_rkey[i]=s_ctrl[WCH+i];
    if(tid<256){
      int n=tid;
      float psi=1.f;
#pragma unroll
      for(int r=0;r<NR;r++) psi *= 1.f - sigf(s_ctrl[384+r])*s_prd[r*256+n];
      s_psi[n]=psi;
      float uo=s_usage[n], pw=s_wdp[n];
      s_usage[n]=(uo+pw-uo*pw)*psi;
    } else if(tid<384){
      int w=tid-256; s_er[w]=sigf(s_ctrl[128+w]);
    } else if(tid>=448 && tid<512){
      int l=tid-448;
      float v=s_ctrl[l]*s_ctrl[l]+s_ctrl[l+64]*s_ctrl[l+64];
      v=waveSum(v);
      if(l==0) s_scal[0]=v;
    }
    __syncthreads();
    if(tid<512){
      int n=tid&255, hf=tid>>8;
      float u2=s_usage[n]*(1.f-EPSF)+EPSF; int c=0;
      for(int jj=0;jj<128;jj++){
        int j=hf*128+jj;
        float uj=s_usage[j]*(1.f-EPSF)+EPSF;
        c += (uj<u2)||(uj==u2 && j<n);
      }
      s_red[hf*256+n]=(float)c;
    }
    __syncthreads();
    if(tid<256){
      myrk=(int)(s_red[tid]+s_red[256+tid]);
      s_su[myrk]=s_usage[tid]*(1.f-EPSF)+EPSF;
    }
    __syncthreads();
    if(tid<16){
      float run=1.f;
#pragma unroll
      for(int i=0;i<16;i++){ int idx=tid*16+i; s_shift[idx]=run; run*=s_su[idx]; }
      s_sct[tid]=run;
    }
    __syncthreads();
    if(tid==0){
      float run=1.f;
      for(int j=0;j<16;j++){ float t2=s_sct[j]; s_sct[j]=run; run*=t2; }
    }
    __syncthreads();
    if(tid<256) allocv=(1.f-s_su[myrk])*s_shift[myrk]*s_sct[myrk>>4];
    if(tid<512){
      int nr=tid>>5, wq=tid&31;
      int n=s*16+nr;
      float4 m=((const float4*)(mem_g + ((size_t)(b*256+n))*WL))[wq];
      int w=wq*4;
      float4 kk=*(const float4*)(s_ctrl+w);
      float dt=m.x*kk.x+m.y*kk.y+m.z*kk.z+m.w*kk.w;
      float m2=m.x*m.x+m.y*m.y+m.z*m.z+m.w*m.w;
      s_red[nr*32+wq]=dt; s_red[512+nr*32+wq]=m2;
    }
    __syncthreads();
    if(tid<16){
      float dt=0,m2=0;
#pragma unroll
      for(int q=0;q<32;q++){ dt+=s_red[tid*32+q]; m2+=s_red[512+tid*32+q]; }
      float wb=oneplusf(s_ctrl[388]);
      float lg=dt*wb/(sqrtf(s_scal[0])*sqrtf(m2)+EPSF);
      g_storef(dots_g+b*256+s*16+tid, lg);
    }
    lbar(bar,b,2*t+1);

    // ============ PHASE D ============
    if(tid<128){
      float2 v=g_loadf2(dots_g+b*256+2*tid);
      s_red[2*tid]=v.x; s_red[2*tid+1]=v.y;
    }
    __syncthreads();
    {
      float lv=s_red[tid&255];
      float mv=waveMax(lv);
      if((tid&63)==0) s_scal[8+(tid>>6)]=mv;   // waves>=8 write 16..23 (unused)
      __syncthreads();
      float mx=s_scal[8]; for(int i=9;i<16;i++) mx=fmaxf(mx,s_scal[i]);
      float ex=expf(lv-mx);
      float sv=waveSum(ex);
      __syncthreads();
      if((tid&63)==0) s_scal[8+(tid>>6)]=sv;
      __syncthreads();
      float se=0; for(int i=8;i<16;i++) se+=s_scal[i]; se*=0.5f;
      if(tid<256){
        float cw=ex/se;
        float ag=sigf(s_ctrl[389]), wg=sigf(s_ctrl[390]);
        s_wdp[tid]=wg*(ag*allocv+(1.f-ag)*cw);
      }
    }
    __syncthreads();
    {
      float wv=waveSum(s_wdp[tid&255]);
      if((tid&63)==0) s_scal[8+(tid>>6)]=wv;
      __syncthreads();
      float swd=0; for(int i=8;i<16;i++) swd+=s_scal[i]; swd*=0.5f;
      if(tid<16) s_preo[tid]=s_prec[s*16+tid];
      __syncthreads();
      if(tid<256) s_prec[tid]=(1.f-swd)*s_prec[tid]+s_wdp[tid];
    }
    __syncthreads();
    if(tid<512){
      int nr=tid>>5, ic=tid&31;
      int n=s*16+nr;
      float wdn=s_wdp[n], pre=s_preo[nr];
      float4* lp=(float4*)(linkT_g+((size_t)(b*256+n))*256);
#pragma unroll
      for(int h2=0;h2<2;h2++){
        int i4=h2*32+ic;
        float4 l=lp[i4];
        int i0=i4*4;
        float4 wv=*(float4*)&s_wdp[i0];
        float4 nl;
        nl.x=(i0  ==n)?0.f:((1.f-wv.x-wdn)*l.x+wv.x*pre);
        nl.y=(i0+1==n)?0.f:((1.f-wv.y-wdn)*l.y+wv.y*pre);
        nl.z=(i0+2==n)?0.f:((1.f-wv.z-wdn)*l.z+wv.z*pre);
        nl.w=(i0+3==n)?0.f:((1.f-wv.w-wdn)*l.w+wv.w*pre);
        lp[i4]=nl;
        *(float4*)&s_link[nr*256+i0]=nl;
      }
    }
    __syncthreads();
    if(tid<512){
      int nr=tid>>5, ic=tid&31;
      float b0=0,b1=0,b2=0,b3=0;
#pragma unroll
      for(int q=0;q<8;q++){
        int i=q*32+ic;
        float l=s_link[nr*256+i];
        b0+=l*s_prd[i]; b1+=l*s_prd[256+i]; b2+=l*s_prd[512+i]; b3+=l*s_prd[768+i];
      }
      s_red[(0*16+nr)*32+ic]=b0; s_red[(1*16+nr)*32+ic]=b1;
      s_red[(2*16+nr)*32+ic]=b2; s_red[(3*16+nr)*32+ic]=b3;
    }
    __syncthreads();
    if(tid<64){
      int r=tid>>4, nr=tid&15;
      float a=0;
#pragma unroll
      for(int q=0;q<32;q++) a+=s_red[(r*16+nr)*32+q];
      g_storef(bwd_g + b*1024 + r*256 + s*16+nr, a);
    }
    if(tid<512){
      int np=tid&255, dh=tid>>8;
      float f0=0,f1=0;
#pragma unroll
      for(int jr=0;jr<16;jr++){
        float l=s_link[jr*256+np];
        int j=s*16+jr;
        f0+=l*s_prd[(2*dh)*256+j];
        f1+=l*s_prd[(2*dh+1)*256+j];
      }
      atomicAdd(facc_g + b*1024 + (2*dh)*256 + np, f0);
      atomicAdd(facc_g + b*1024 + (2*dh+1)*256 + np, f1);
    }
    if(tid<512){
      int nr=tid>>5, wq=tid&31;
      int n=s*16+nr;
      float ps=s_psi[n], wdn=s_wdp[n];
      float4* mr=(float4*)(mem_g+((size_t)(b*256+n))*WL);
      float4 m=mr[wq]; int w=wq*4;
      float4 er=*(const float4*)(s_er+w);
      float4 wv=*(const float4*)(s_ctrl+256+w);
      m.x=m.x*ps*(1.f-wdn*er.x)+wdn*wv.x;
      m.y=m.y*ps*(1.f-wdn*er.y)+wdn*wv.y;
      m.z=m.z*ps*(1.f-wdn*er.z)+wdn*wv.z;
      m.w=m.w*ps*(1.f-wdn*er.w)+wdn*wv.w;
      mr[wq]=m;
      *(float4*)&s_mem[nr*128+w]=m;
    }
    __syncthreads();
    if(tid<512){
      int nr=tid>>5, wq=tid&31;
      float4 m=*(float4*)&s_mem[nr*128+wq*4];
      int w=wq*4;
      float4 k0=*(const float4*)(s_rkey+w);
      float4 k1=*(const float4*)(s_rkey+132+w);
      float4 k2=*(const float4*)(s_rkey+264+w);
      float4 k3=*(const float4*)(s_rkey+396+w);
      float d0=m.x*k0.x+m.y*k0.y+m.z*k0.z+m.w*k0.w;
      float d1=m.x*k1.x+m.y*k1.y+m.z*k1.z+m.w*k1.w;
      float d2=m.x*k2.x+m.y*k2.y+m.z*k2.z+m.w*k2.w;
      float d3=m.x*k3.x+m.y*k3.y+m.z*k3.z+m.w*k3.w;
      float m2=m.x*m.x+m.y*m.y+m.z*m.z+m.w*m.w;
      s_red[(0*16+nr)*32+wq]=d0; s_red[(1*16+nr)*32+wq]=d1;
      s_red[(2*16+nr)*32+wq]=d2; s_red[(3*16+nr)*32+wq]=d3;
      s_red[2048+nr*32+wq]=m2;
    }
    if(tid<256){
      int r=tid>>6, l=tid&63;
      const float* kk=s_rkey+r*132;
      float kv=kk[l]*kk[l]+kk[l+64]*kk[l+64];
      kv=waveSum(kv);
      if(l==0) s_scal[4+r]=sqrtf(kv);
    }
    __syncthreads();
    if(tid<16){
      float m2=0;
#pragma unroll
      for(int q=0;q<32;q++) m2+=s_red[2048+tid*32+q];
      s_mn[tid]=sqrtf(m2);
    }
    __syncthreads();
    if(tid<64){
      int r=tid>>4, nr=tid&15;
      float dt=0;
#pragma unroll
      for(int q=0;q<32;q++) dt+=s_red[(r*16+nr)*32+q];
      float rb=oneplusf(s_rkey[r*132+128]);
      float lg=dt*rb/(s_scal[4+r]*s_mn[nr]+EPSF);
      g_storef(rlog_g+b*1024+r*256+s*16+nr,lg);
    }
    lbar(bar,b,2*t+2);

    // ============ PHASE E ============
    for(int i=tid;i<512;i+=THR){
      float2 v=g_loadf2(facc_g + b*1024 + 2*i);
      s_fwd[2*i]=v.x; s_fwd[2*i+1]=v.y;
    }
    for(int i=tid;i<512;i+=THR){
      float2 v=g_loadf2(bwd_g+b*1024+2*i);
      s_bwd[2*i]=v.x; s_bwd[2*i+1]=v.y;
    }
    for(int i=tid;i<512;i+=THR){
      float2 v=g_loadf2(rlog_g+b*1024+2*i);
      s_red[2*i]=v.x; s_red[2*i+1]=v.y;
    }
    __syncthreads();
    if(tid<512){   // sharpen: wave w -> row (0-3 fwd, 4-7 bwd)
      int l=tid&63, w=tid>>6;
      float* rp=(w<4)? (s_fwd+w*256) : (s_bwd+(w-4)*256);
      float a=rp[l]+EPSF, b2=rp[l+64]+EPSF, c2=rp[l+128]+EPSF, d2=rp[l+192]+EPSF;
      float mxr=waveMax(fmaxf(fmaxf(a,b2),fmaxf(c2,d2)));
      mxr=__shfl(mxr,0,64);
      float ff=oneplusf(s_ctrl[919+w]);
      a=powf(a/mxr,ff); b2=powf(b2/mxr,ff); c2=powf(c2/mxr,ff); d2=powf(d2/mxr,ff);
      float sm=waveSum(a+b2+c2+d2);
      sm=__shfl(sm,0,64);
      float inv=1.f/sm;
      rp[l]=a*inv; rp[l+64]=b2*inv; rp[l+128]=c2*inv; rp[l+192]=d2*inv;
    }
    if(tid<256){   // read softmax: wave w<4 owns row w (race-free)
      int l=tid&63, w=tid>>6;
      float* rr=s_red+w*256;
      float a=rr[l],b2=rr[l+64],c2=rr[l+128],d2=rr[l+192];
      float mx2=waveMax(fmaxf(fmaxf(a,b2),fmaxf(c2,d2)));
      mx2=__shfl(mx2,0,64);
      a=expf(a-mx2); b2=expf(b2-mx2); c2=expf(c2-mx2); d2=expf(d2-mx2);
      float sm=waveSum(a+b2+c2+d2);
      sm=__shfl(sm,0,64);
      float inv=1.f/sm;
      rr[l]=a*inv; rr[l+64]=b2*inv; rr[l+128]=c2*inv; rr[l+192]=d2*inv;
    }
    __syncthreads();
    if(tid<256){
      int n=tid;
#pragma unroll
      for(int r=0;r<NR;r++){
        float cr=s_red[r*256+n];
        float fw=s_fwd[r*256+n];
        float bw=s_bwd[r*256+n];
        int mo=WCH+r*132+129;
        float m0=s_ctrl[mo],m1=s_ctrl[mo+1],m2s=s_ctrl[mo+2];
        float mm=fmaxf(m0,fmaxf(m1,m2s));
        float e0=expf(m0-mm),e1=expf(m1-mm),e2=expf(m2s-mm);
        float es=e0+e1+e2;
        s_prd[r*256+n]=(e0*bw+e1*cr+e2*fw)/es;
      }
    }
    __syncthreads();
    if(tid<512){
      int w=tid&127, nq=tid>>7;
      float a0=0,a1=0,a2=0,a3=0;
#pragma unroll
      for(int q=0;q<4;q++){
        int nr=nq*4+q; int n=s*16+nr;
        float mv=s_mem[nr*128+w];
        a0+=s_prd[n]*mv; a1+=s_prd[256+n]*mv; a2+=s_prd[512+n]*mv; a3+=s_prd[768+n]*mv;
      }
      s_red[(0*4+nq)*128+w]=a0; s_red[(1*4+nq)*128+w]=a1;
      s_red[(2*4+nq)*128+w]=a2; s_red[(3*4+nq)*128+w]=a3;
    }
    __syncthreads();
    if(tid<512){
      int r=tid>>7, w=tid&127;
      float rd=s_red[(r*4+0)*128+w]+s_red[(r*4+1)*128+w]+s_red[(r*4+2)*128+w]+s_red[(r*4+3)*128+w];
      atomicAdd(racc_rot + (size_t)(t+1)*8192 + b*512 + r*128 + w, rd);
    }
    gbarH(bar,b,3*t+3);
  }
}

extern "C" void kernel_launch(void* const* d_in, const int* in_sizes, int n_in,
                              void* d_out, int out_size, void* d_ws, size_t ws_size,
                              hipStream_t stream) {
  const float* in_data = (const float*)d_in[0];
  const float* Wx      = (const float*)d_in[1];
  const float* Wh      = (const float*)d_in[2];
  const float* b_lstm  = (const float*)d_in[3];
  const float* Wc      = (const float*)d_in[4];
  const float* bc      = (const float*)d_in[5];
  const float* Wo      = (const float*)d_in[6];
  const float* bo      = (const float*)d_in[7];
  const float* Wr      = (const float*)d_in[8];
  const float* br      = (const float*)d_in[9];
  float* out = (float*)d_out;
  float* ws  = (float*)d_ws;

  size_t off=0;
  float* mem_     = ws+off; off += (size_t)NB*NC*WL;       // 524288
  float* linkT_   = ws+off; off += (size_t)NB*NC*NC;       // 1048576
  float* racc_rot = ws+off; off += (size_t)65*8192;        // 532480
  float* h_rot    = ws+off; off += (size_t)65*8192;        // 532480
  float* ctrl_rot = ws+off; off += (size_t)64*14848;       // 950272
  float* dots_    = ws+off; off += NB*NC;
  float* bwd_     = ws+off; off += NB*NR*NC;
  float* facc_    = ws+off; off += NB*NR*NC;
  float* rlog_    = ws+off; off += NB*NR*NC;
  int*   bar_     = (int*)(ws+off); off += 2048;
  size_t zero_floats = off;                                // ~3.64M floats = 14.6 MB

  static const size_t SH_BYTES = (size_t)SH_FLOATS*sizeof(float);  // 153,344 B
  hipFuncSetAttribute((const void*)k_persist,
                      hipFuncAttributeMaxDynamicSharedMemorySize, (int)SH_BYTES);

  k_zero<<<256,256,0,stream>>>(ws, zero_floats);
  k_persist<<<NBLK,THR,SH_BYTES,stream>>>(Wx,Wh,b_lstm,Wc,bc,Wo,bo,Wr,br,in_data,
                                          mem_,linkT_,racc_rot,h_rot,ctrl_rot,
                                          dots_,bwd_,facc_,rlog_,out,bar_);
}

// Round 19
// 3006.443 us; speedup vs baseline: 1.0479x; 1.0479x over previous
//
#include <hip/hip_runtime.h>
#include <math.h>

#define NT   64
#define NB   16
#define OUTS 256
#define WL   128
#define NC   256
#define NR   4
#define HIDN 512
#define G4   2048
#define KTOT 1280
#define WCH  391
#define COUT 927
#define EPSF 1e-6f
#define NBLK 256
#define THR  512

// LDS float offsets (weight rows padded off power-of-2 strides)
#define O_WG    0        // 10272: gates W [c][1284]
#define O_WCc   10272    // 2064 : ctrl W [cl][516]
#define O_WOc   12336    // 1024 : out W [k2]
#define O_PRD   13360    // 1024
#define O_USG   14384    // 256
#define O_PRC   14640    // 256
#define O_WDP   14896    // 256
#define O_COWN  15152    // 32
#define O_RED   15184    // 2560
#define O_SCAL  17744    // 32
#define O_SCT   17776    // 16
#define O_UNI   17792    // 20576 union: act[16][1284] | C/D/E scratch
#define SH_FLOATS 38336  // 153,344 B

__device__ __forceinline__ float sigf(float x){ return 1.0f/(1.0f+expf(-x)); }
__device__ __forceinline__ float oneplusf(float x){ return fmaxf(x,0.0f)+log1pf(expf(-fabsf(x)))+1.0f; }

__device__ __forceinline__ float waveSum(float v){
#pragma unroll
  for(int o=32;o>0;o>>=1) v += __shfl_down(v,o,64);
  return v;
}
__device__ __forceinline__ float waveMax(float v){
#pragma unroll
  for(int o=32;o>0;o>>=1) v = fmaxf(v,__shfl_down(v,o,64));
  return v;
}

__device__ __forceinline__ void g_storef(float* p, float v){
  __hip_atomic_store(p, v, __ATOMIC_RELAXED, __HIP_MEMORY_SCOPE_AGENT);
}
__device__ __forceinline__ float2 g_loadf2(const float* p){
  unsigned long long v = __hip_atomic_load((const unsigned long long*)p, __ATOMIC_RELAXED, __HIP_MEMORY_SCOPE_AGENT);
  union{unsigned long long u; float2 f;} c; c.u=v; return c.f;
}

// ---- single-writer monotonic flag barriers (no atomic RMW) ----
// flagA[256]: per-block phase counter; flagB[16]: per-batch leader counter.
__device__ __forceinline__ void bar_local(int* flagA, int b, int s, int pc){
  __syncthreads();
  if (threadIdx.x < 64){
    int l = threadIdx.x;
    if (l == 0){
      asm volatile("s_waitcnt vmcnt(0) lgkmcnt(0)" ::: "memory");
      __hip_atomic_store(flagA + b*16 + s, pc, __ATOMIC_RELAXED, __HIP_MEMORY_SCOPE_AGENT);
    }
    if (l < 16){
      while (__hip_atomic_load(flagA + b*16 + l, __ATOMIC_RELAXED, __HIP_MEMORY_SCOPE_AGENT) < pc)
        __builtin_amdgcn_s_sleep(1);
    }
    asm volatile("" ::: "memory");
  }
  __syncthreads();
}
__device__ __forceinline__ void bar_global(int* flagA, int* flagB, int b, int s, int pc){
  __syncthreads();
  if (threadIdx.x < 64){
    int l = threadIdx.x;
    if (l == 0){
      asm volatile("s_waitcnt vmcnt(0) lgkmcnt(0)" ::: "memory");
      __hip_atomic_store(flagA + b*16 + s, pc, __ATOMIC_RELAXED, __HIP_MEMORY_SCOPE_AGENT);
    }
    if (s == 0){                       // batch leader: gather own batch, publish
      if (l < 16){
        while (__hip_atomic_load(flagA + b*16 + l, __ATOMIC_RELAXED, __HIP_MEMORY_SCOPE_AGENT) < pc)
          __builtin_amdgcn_s_sleep(1);
      }
      if (l == 0)
        __hip_atomic_store(flagB + b, pc, __ATOMIC_RELAXED, __HIP_MEMORY_SCOPE_AGENT);
    }
    if (l < 16){
      while (__hip_atomic_load(flagB + l, __ATOMIC_RELAXED, __HIP_MEMORY_SCOPE_AGENT) < pc)
        __builtin_amdgcn_s_sleep(1);
    }
    asm volatile("" ::: "memory");
  }
  __syncthreads();
}

__global__ void k_zero(float* p, size_t n){
  size_t i = (size_t)blockIdx.x*blockDim.x + threadIdx.x;
  size_t st = (size_t)gridDim.x*blockDim.x;
  for(; i<n; i+=st) p[i]=0.0f;
}

__global__ __launch_bounds__(THR,1) void k_persist(
    const float* __restrict__ Wx, const float* __restrict__ Wh, const float* __restrict__ b_lstm,
    const float* __restrict__ Wc, const float* __restrict__ bc,
    const float* __restrict__ Wo, const float* __restrict__ bo,
    const float* __restrict__ Wr, const float* __restrict__ br,
    const float* __restrict__ in_data,
    float* mem_g, float* linkT_g, float* racc_rot, float* h_rot, float* ctrl_rot,
    float* dots_g, float* bwd_g, float* facc_g, float* rlog_g,
    float* out_g, int* bar)
{
  extern __shared__ float SH[];
  float* s_wg   = SH + O_WG;
  float* s_wc   = SH + O_WCc;
  float* s_wo   = SH + O_WOc;
  float* s_prd  = SH + O_PRD;
  float* s_usage= SH + O_USG;
  float* s_prec = SH + O_PRC;
  float* s_wdp  = SH + O_WDP;
  float* s_cown = SH + O_COWN;
  float* s_red  = SH + O_RED;
  float* s_scal = SH + O_SCAL;
  float* s_sct  = SH + O_SCT;
  float* s_act  = SH + O_UNI;            // [16][1284]
  float* s_ctrl = SH + O_UNI;
  float* s_psi  = SH + O_UNI + 928;
  float* s_su   = SH + O_UNI + 1184;
  float* s_shift= SH + O_UNI + 1440;
  float* s_er   = SH + O_UNI + 1696;
  float* s_mn   = SH + O_UNI + 1824;
  float* s_preo = SH + O_UNI + 1840;
  float* s_link = SH + O_UNI + 1856;     // 4096
  float* s_mem  = SH + O_UNI + 5952;     // 2048
  float* s_fwd  = SH + O_UNI + 8000;     // 1024
  float* s_bwd  = SH + O_UNI + 9024;     // 1024
  float* s_rkey = SH + O_UNI + 10048;    // 528 aligned read-key copy

  const int tid = threadIdx.x, bk = blockIdx.x;
  const int s = bk & 15, b = bk >> 4;
  int* flagA = bar;        // 256 ints
  int* flagB = bar + 256;  // 16 ints
  int pc = 0;

  // ---- one-time LDS weight loads ----
  for(int i=tid;i<10240;i+=THR){
    int c=i&7, k=i>>3;
    int col=(c>>1)*512 + 2*bk + (c&1);
    s_wg[c*1284+k] = (k<768) ? Wx[(size_t)k*G4+col] : Wh[(size_t)(k-768)*G4+col];
  }
  for(int i=tid;i<2048;i+=THR){
    int cl=i&3, k=i>>2;
    int j=4*bk+cl;
    s_wc[cl*516+k] = (bk<232 && j<COUT) ? Wc[(size_t)k*COUT+j] : 0.f;
  }
  for(int i=tid;i<1024;i+=THR){
    s_wo[i] = (i<512) ? Wr[(size_t)i*OUTS+bk] : Wo[(size_t)(i-512)*OUTS+bk];
  }
  for(int i=tid;i<1024;i+=THR) s_prd[i]=0.f;
  for(int i=tid;i<256;i+=THR){ s_usage[i]=0.f; s_prec[i]=0.f; s_wdp[i]=0.f; }
  if(tid<32) s_cown[tid]=0.f;
  __syncthreads();

  int myrk=0; float allocv=0.f;

  for(int t=0;t<=NT;t++){
    // ============ PHASE A: stage act, gates GEMM, LSTM, out(t-1), zero facc ============
    if(t<NT){
      for(int i=tid;i<1024;i+=THR){
        int bi=i>>6, k4=(i&63)*4;
        float4 v = *(const float4*)(in_data + (size_t)t*4096 + bi*256 + k4);
        *(float4*)&s_act[bi*1284+k4] = v;
      }
    }
    for(int i=tid;i<2048;i+=THR){
      int bi=i>>7, k4=(i&127)*4;
      float4 v = *(const float4*)(racc_rot + (size_t)t*8192 + bi*512 + k4);
      *(float4*)&s_act[bi*1284+256+k4] = v;
    }
    for(int i=tid;i<2048;i+=THR){
      int bi=i>>7, k4=(i&127)*4;
      float4 v = *(const float4*)(h_rot + (size_t)t*8192 + bi*512 + k4);
      *(float4*)&s_act[bi*1284+768+k4] = v;
    }
    if(tid<64) g_storef(facc_g + b*1024 + s*64 + tid, 0.0f);
    __syncthreads();
    if(t<NT){
      int oc=tid&127, q=tid>>7;            // 4 k-splits of 320
      int c=oc>>4, bi=oc&15;
      const float* ap = s_act + bi*1284;
      const float* wp = s_wg + c*1284;
      float4 a4={0,0,0,0};
      int k0=q*320;
#pragma unroll 8
      for(int it=0;it<80;it++){
        int k=k0+it*4;
        float4 a=*(const float4*)(ap+k);
        float4 w=*(const float4*)(wp+k);
        a4.x+=a.x*w.x; a4.y+=a.y*w.y; a4.z+=a.z*w.z; a4.w+=a.w*w.w;
      }
      s_red[q*128+oc]=a4.x+a4.y+a4.z+a4.w;
    }
    if(t>0){
      int bi=tid>>5, q=tid&31;             // 32 lanes x 32 iters covers K=1024
      const float* ap = s_act + bi*1284 + 256;
      float acc=0.f;
#pragma unroll 8
      for(int it=0;it<32;it++){
        int k2=q+it*32;                    // stride-1 per lane
        acc += ap[k2]*s_wo[k2];
      }
      s_red[512 + bi*32 + q] = acc;
    }
    __syncthreads();
    if(t<NT && tid<32){
      int j2=tid>>4, bi=tid&15;
      float g4[4];
#pragma unroll
      for(int g=0;g<4;g++){
        int c=g*2+j2;
        float v=0.f;
#pragma unroll
        for(int q=0;q<4;q++) v += s_red[q*128+c*16+bi];
        v += b_lstm[g*512 + 2*bk + j2];
        g4[g]=v;
      }
      float cc = sigf(g4[1])*s_cown[j2*16+bi] + sigf(g4[0])*tanhf(g4[2]);
      float hh = sigf(g4[3])*tanhf(cc);
      s_cown[j2*16+bi]=cc;
      g_storef(h_rot + (size_t)(t+1)*8192 + bi*512 + 2*bk + j2, hh);
    }
    if(t>0 && tid>=64 && tid<80){
      int bi=tid-64;
      float acc=bo[bk]+br[bk];
#pragma unroll
      for(int q=0;q<32;q++) acc += s_red[512+bi*32+q];
      out_g[((size_t)(t-1)*NB+bi)*OUTS + bk] = acc;
    }
    if(t==NT) break;
    bar_global(flagA,flagB,b,s,++pc);

    // ============ PHASE B: ctrl GEMM ============
    for(int i=tid;i<2048;i+=THR){
      int bi=i>>7, k4=(i&127)*4;
      float4 v = *(const float4*)(h_rot + (size_t)(t+1)*8192 + bi*512 + k4);
      *(float4*)&s_act[bi*1284+768+k4] = v;
    }
    __syncthreads();
    if(bk<232){
      int o=tid&63, ks=tid>>6;             // 8 k-splits of 64
      int cl=o>>4, bi=o&15;
      int j=4*bk+cl;
      float acc=0.f;
      if(j<COUT){
        const float* ap=s_act+bi*1284+768;
        const float* wp=s_wc+cl*516;
#pragma unroll
        for(int kk=0;kk<16;kk++){
          int k=ks*64+kk*4;
          float4 a=*(const float4*)(ap+k);
          float4 w=*(const float4*)(wp+k);
          acc += a.x*w.x+a.y*w.y+a.z*w.z+a.w*w.w;
        }
      }
      s_red[ks*64+o]=acc;
    }
    __syncthreads();
    if(bk<232 && tid<64){
      int cl=tid>>4, bi=tid&15; int j=4*bk+cl;
      if(j<COUT){
        float a=bc[j];
#pragma unroll
        for(int ks=0;ks<8;ks++) a+=s_red[ks*64+tid];
        g_storef(ctrl_rot + (size_t)t*14848 + bi*928 + j, fminf(fmaxf(a,-20.f),20.f));
      }
    }
    bar_global(flagA,flagB,b,s,++pc);

    // ============ PHASE C: psi/usage/alloc + write-key dots ============
    for(int i=tid;i<232;i+=THR){
      float4 v = *(const float4*)(ctrl_rot + (size_t)t*14848 + b*928 + 4*i);
      *(float4*)&s_ctrl[4*i] = v;
    }
    __syncthreads();
    for(int i=tid;i<528;i+=THR) s_rkey[i]=s_ctrl[WCH+i];
    if(tid<256){
      int n=tid;
      float psi=1.f;
#pragma unroll
      for(int r=0;r<NR;r++) psi *= 1.f - sigf(s_ctrl[384+r])*s_prd[r*256+n];
      s_psi[n]=psi;
      float uo=s_usage[n], pw=s_wdp[n];
      s_usage[n]=(uo+pw-uo*pw)*psi;
    } else if(tid<384){
      int w=tid-256; s_er[w]=sigf(s_ctrl[128+w]);
    } else if(tid>=448){
      int l=tid-448;
      float v=s_ctrl[l]*s_ctrl[l]+s_ctrl[l+64]*s_ctrl[l+64];
      v=waveSum(v);
      if(l==0) s_scal[0]=v;
    }
    __syncthreads();
    {
      int n=tid&255, hf=tid>>8;
      float u2=s_usage[n]*(1.f-EPSF)+EPSF; int c=0;
      for(int jj=0;jj<128;jj++){
        int j=hf*128+jj;
        float uj=s_usage[j]*(1.f-EPSF)+EPSF;
        c += (uj<u2)||(uj==u2 && j<n);
      }
      s_red[hf*256+n]=(float)c;
    }
    __syncthreads();
    if(tid<256){
      myrk=(int)(s_red[tid]+s_red[256+tid]);
      s_su[myrk]=s_usage[tid]*(1.f-EPSF)+EPSF;
    }
    __syncthreads();
    if(tid<16){
      float run=1.f;
#pragma unroll
      for(int i=0;i<16;i++){ int idx=tid*16+i; s_shift[idx]=run; run*=s_su[idx]; }
      s_sct[tid]=run;
    }
    __syncthreads();
    if(tid==0){
      float run=1.f;
      for(int j=0;j<16;j++){ float t2=s_sct[j]; s_sct[j]=run; run*=t2; }
    }
    __syncthreads();
    if(tid<256) allocv=(1.f-s_su[myrk])*s_shift[myrk]*s_sct[myrk>>4];
    {
      int nr=tid>>5, wq=tid&31;
      int n=s*16+nr;
      float4 m=((const float4*)(mem_g + ((size_t)(b*256+n))*WL))[wq];
      int w=wq*4;
      float4 kk=*(const float4*)(s_ctrl+w);
      float dt=m.x*kk.x+m.y*kk.y+m.z*kk.z+m.w*kk.w;
      float m2=m.x*m.x+m.y*m.y+m.z*m.z+m.w*m.w;
      s_red[nr*32+wq]=dt; s_red[512+nr*32+wq]=m2;
    }
    __syncthreads();
    if(tid<16){
      float dt=0,m2=0;
#pragma unroll
      for(int q=0;q<32;q++){ dt+=s_red[tid*32+q]; m2+=s_red[512+tid*32+q]; }
      float wb=oneplusf(s_ctrl[388]);
      float lg=dt*wb/(sqrtf(s_scal[0])*sqrtf(m2)+EPSF);
      g_storef(dots_g+b*256+s*16+tid, lg);
    }
    bar_local(flagA,b,s,++pc);

    // ============ PHASE D ============
    if(tid<128){
      float2 v=g_loadf2(dots_g+b*256+2*tid);
      s_red[2*tid]=v.x; s_red[2*tid+1]=v.y;
    }
    __syncthreads();
    {
      float lv=s_red[tid&255];
      float mv=waveMax(lv);
      if((tid&63)==0) s_scal[8+(tid>>6)]=mv;
      __syncthreads();
      float mx=s_scal[8]; for(int i=9;i<16;i++) mx=fmaxf(mx,s_scal[i]);
      float ex=expf(lv-mx);
      float sv=waveSum(ex);
      __syncthreads();
      if((tid&63)==0) s_scal[8+(tid>>6)]=sv;
      __syncthreads();
      float se=0; for(int i=8;i<16;i++) se+=s_scal[i]; se*=0.5f;
      if(tid<256){
        float cw=ex/se;
        float ag=sigf(s_ctrl[389]), wg=sigf(s_ctrl[390]);
        s_wdp[tid]=wg*(ag*allocv+(1.f-ag)*cw);
      }
    }
    __syncthreads();
    {
      float wv=waveSum(s_wdp[tid&255]);
      if((tid&63)==0) s_scal[8+(tid>>6)]=wv;
      __syncthreads();
      float swd=0; for(int i=8;i<16;i++) swd+=s_scal[i]; swd*=0.5f;
      if(tid<16) s_preo[tid]=s_prec[s*16+tid];
      __syncthreads();
      if(tid<256) s_prec[tid]=(1.f-swd)*s_prec[tid]+s_wdp[tid];
    }
    __syncthreads();
    {
      int nr=tid>>5, ic=tid&31;
      int n=s*16+nr;
      float wdn=s_wdp[n], pre=s_preo[nr];
      float4* lp=(float4*)(linkT_g+((size_t)(b*256+n))*256);
#pragma unroll
      for(int h2=0;h2<2;h2++){
        int i4=h2*32+ic;
        float4 l=lp[i4];
        int i0=i4*4;
        float4 wv=*(float4*)&s_wdp[i0];
        float4 nl;
        nl.x=(i0  ==n)?0.f:((1.f-wv.x-wdn)*l.x+wv.x*pre);
        nl.y=(i0+1==n)?0.f:((1.f-wv.y-wdn)*l.y+wv.y*pre);
        nl.z=(i0+2==n)?0.f:((1.f-wv.z-wdn)*l.z+wv.z*pre);
        nl.w=(i0+3==n)?0.f:((1.f-wv.w-wdn)*l.w+wv.w*pre);
        lp[i4]=nl;
        *(float4*)&s_link[nr*256+i0]=nl;
      }
    }
    __syncthreads();
    {   // bwd (owned n, i = q*32+ic : bank-conflict-free)
      int nr=tid>>5, ic=tid&31;
      float b0=0,b1=0,b2=0,b3=0;
#pragma unroll
      for(int q=0;q<8;q++){
        int i=q*32+ic;
        float l=s_link[nr*256+i];
        b0+=l*s_prd[i]; b1+=l*s_prd[256+i]; b2+=l*s_prd[512+i]; b3+=l*s_prd[768+i];
      }
      s_red[(0*16+nr)*32+ic]=b0; s_red[(1*16+nr)*32+ic]=b1;
      s_red[(2*16+nr)*32+ic]=b2; s_red[(3*16+nr)*32+ic]=b3;
    }
    __syncthreads();
    if(tid<64){
      int r=tid>>4, nr=tid&15;
      float a=0;
#pragma unroll
      for(int q=0;q<32;q++) a+=s_red[(r*16+nr)*32+q];
      g_storef(bwd_g + b*1024 + r*256 + s*16+nr, a);
    }
    {
      int np=tid&255, dh=tid>>8;
      float f0=0,f1=0;
#pragma unroll
      for(int jr=0;jr<16;jr++){
        float l=s_link[jr*256+np];
        int j=s*16+jr;
        f0+=l*s_prd[(2*dh)*256+j];
        f1+=l*s_prd[(2*dh+1)*256+j];
      }
      atomicAdd(facc_g + b*1024 + (2*dh)*256 + np, f0);
      atomicAdd(facc_g + b*1024 + (2*dh+1)*256 + np, f1);
    }
    {
      int nr=tid>>5, wq=tid&31;
      int n=s*16+nr;
      float ps=s_psi[n], wdn=s_wdp[n];
      float4* mr=(float4*)(mem_g+((size_t)(b*256+n))*WL);
      float4 m=mr[wq]; int w=wq*4;
      float4 er=*(const float4*)(s_er+w);
      float4 wv=*(const float4*)(s_ctrl+256+w);
      m.x=m.x*ps*(1.f-wdn*er.x)+wdn*wv.x;
      m.y=m.y*ps*(1.f-wdn*er.y)+wdn*wv.y;
      m.z=m.z*ps*(1.f-wdn*er.z)+wdn*wv.z;
      m.w=m.w*ps*(1.f-wdn*er.w)+wdn*wv.w;
      mr[wq]=m;
      *(float4*)&s_mem[nr*128+w]=m;
    }
    __syncthreads();
    {
      int nr=tid>>5, wq=tid&31;
      float4 m=*(float4*)&s_mem[nr*128+wq*4];
      int w=wq*4;
      float4 k0=*(const float4*)(s_rkey+w);
      float4 k1=*(const float4*)(s_rkey+132+w);
      float4 k2=*(const float4*)(s_rkey+264+w);
      float4 k3=*(const float4*)(s_rkey+396+w);
      float d0=m.x*k0.x+m.y*k0.y+m.z*k0.z+m.w*k0.w;
      float d1=m.x*k1.x+m.y*k1.y+m.z*k1.z+m.w*k1.w;
      float d2=m.x*k2.x+m.y*k2.y+m.z*k2.z+m.w*k2.w;
      float d3=m.x*k3.x+m.y*k3.y+m.z*k3.z+m.w*k3.w;
      float m2=m.x*m.x+m.y*m.y+m.z*m.z+m.w*m.w;
      s_red[(0*16+nr)*32+wq]=d0; s_red[(1*16+nr)*32+wq]=d1;
      s_red[(2*16+nr)*32+wq]=d2; s_red[(3*16+nr)*32+wq]=d3;
      s_red[2048+nr*32+wq]=m2;
    }
    if(tid<256){
      int r=tid>>6, l=tid&63;
      const float* kk=s_rkey+r*132;
      float kv=kk[l]*kk[l]+kk[l+64]*kk[l+64];
      kv=waveSum(kv);
      if(l==0) s_scal[4+r]=sqrtf(kv);
    }
    __syncthreads();
    if(tid<16){
      float m2=0;
#pragma unroll
      for(int q=0;q<32;q++) m2+=s_red[2048+tid*32+q];
      s_mn[tid]=sqrtf(m2);
    }
    __syncthreads();
    if(tid<64){
      int r=tid>>4, nr=tid&15;
      float dt=0;
#pragma unroll
      for(int q=0;q<32;q++) dt+=s_red[(r*16+nr)*32+q];
      float rb=oneplusf(s_rkey[r*132+128]);
      float lg=dt*rb/(s_scal[4+r]*s_mn[nr]+EPSF);
      g_storef(rlog_g+b*1024+r*256+s*16+nr,lg);
    }
    bar_local(flagA,b,s,++pc);

    // ============ PHASE E ============
    {
      float2 v=g_loadf2(facc_g + b*1024 + 2*tid);
      s_fwd[2*tid]=v.x; s_fwd[2*tid+1]=v.y;
    }
    {
      float2 v=g_loadf2(bwd_g+b*1024+2*tid);
      s_bwd[2*tid]=v.x; s_bwd[2*tid+1]=v.y;
    }
    {
      float2 v=g_loadf2(rlog_g+b*1024+2*tid);
      s_red[2*tid]=v.x; s_red[2*tid+1]=v.y;
    }
    __syncthreads();
    {   // sharpen: wave w -> row (0-3 fwd, 4-7 bwd)
      int l=tid&63, w=tid>>6;
      float* rp=(w<4)? (s_fwd+w*256) : (s_bwd+(w-4)*256);
      float a=rp[l]+EPSF, b2=rp[l+64]+EPSF, c2=rp[l+128]+EPSF, d2=rp[l+192]+EPSF;
      float mxr=waveMax(fmaxf(fmaxf(a,b2),fmaxf(c2,d2)));
      mxr=__shfl(mxr,0,64);
      float ff=oneplusf(s_ctrl[919+w]);
      a=powf(a/mxr,ff); b2=powf(b2/mxr,ff); c2=powf(c2/mxr,ff); d2=powf(d2/mxr,ff);
      float sm=waveSum(a+b2+c2+d2);
      sm=__shfl(sm,0,64);
      float inv=1.f/sm;
      rp[l]=a*inv; rp[l+64]=b2*inv; rp[l+128]=c2*inv; rp[l+192]=d2*inv;
    }
    if(tid<256){   // read softmax: wave w<4 owns row w (race-free)
      int l=tid&63, w=tid>>6;
      float* rr=s_red+w*256;
      float a=rr[l],b2=rr[l+64],c2=rr[l+128],d2=rr[l+192];
      float mx2=waveMax(fmaxf(fmaxf(a,b2),fmaxf(c2,d2)));
      mx2=__shfl(mx2,0,64);
      a=expf(a-mx2); b2=expf(b2-mx2); c2=expf(c2-mx2); d2=expf(d2-mx2);
      float sm=waveSum(a+b2+c2+d2);
      sm=__shfl(sm,0,64);
      float inv=1.f/sm;
      rr[l]=a*inv; rr[l+64]=b2*inv; rr[l+128]=c2*inv; rr[l+192]=d2*inv;
    }
    __syncthreads();
    if(tid<256){
      int n=tid;
#pragma unroll
      for(int r=0;r<NR;r++){
        float cr=s_red[r*256+n];
        float fw=s_fwd[r*256+n];
        float bw=s_bwd[r*256+n];
        int mo=WCH+r*132+129;
        float m0=s_ctrl[mo],m1=s_ctrl[mo+1],m2s=s_ctrl[mo+2];
        float mm=fmaxf(m0,fmaxf(m1,m2s));
        float e0=expf(m0-mm),e1=expf(m1-mm),e2=expf(m2s-mm);
        float es=e0+e1+e2;
        s_prd[r*256+n]=(e0*bw+e1*cr+e2*fw)/es;
      }
    }
    __syncthreads();
    {
      int w=tid&127, nq=tid>>7;
      float a0=0,a1=0,a2=0,a3=0;
#pragma unroll
      for(int q=0;q<4;q++){
        int nr=nq*4+q; int n=s*16+nr;
        float mv=s_mem[nr*128+w];
        a0+=s_prd[n]*mv; a1+=s_prd[256+n]*mv; a2+=s_prd[512+n]*mv; a3+=s_prd[768+n]*mv;
      }
      s_red[(0*4+nq)*128+w]=a0; s_red[(1*4+nq)*128+w]=a1;
      s_red[(2*4+nq)*128+w]=a2; s_red[(3*4+nq)*128+w]=a3;
    }
    __syncthreads();
    {
      int r=tid>>7, w=tid&127;
      float rd=s_red[(r*4+0)*128+w]+s_red[(r*4+1)*128+w]+s_red[(r*4+2)*128+w]+s_red[(r*4+3)*128+w];
      atomicAdd(racc_rot + (size_t)(t+1)*8192 + b*512 + r*128 + w, rd);
    }
    bar_global(flagA,flagB,b,s,++pc);
  }
}

extern "C" void kernel_launch(void* const* d_in, const int* in_sizes, int n_in,
                              void* d_out, int out_size, void* d_ws, size_t ws_size,
                              hipStream_t stream) {
  const float* in_data = (const float*)d_in[0];
  const float* Wx      = (const float*)d_in[1];
  const float* Wh      = (const float*)d_in[2];
  const float* b_lstm  = (const float*)d_in[3];
  const float* Wc      = (const float*)d_in[4];
  const float* bc      = (const float*)d_in[5];
  const float* Wo      = (const float*)d_in[6];
  const float* bo      = (const float*)d_in[7];
  const float* Wr      = (const float*)d_in[8];
  const float* br      = (const float*)d_in[9];
  float* out = (float*)d_out;
  float* ws  = (float*)d_ws;

  size_t off=0;
  float* mem_     = ws+off; off += (size_t)NB*NC*WL;       // 524288
  float* linkT_   = ws+off; off += (size_t)NB*NC*NC;       // 1048576
  float* racc_rot = ws+off; off += (size_t)65*8192;        // 532480
  float* h_rot    = ws+off; off += (size_t)65*8192;        // 532480
  float* ctrl_rot = ws+off; off += (size_t)64*14848;       // 950272
  float* dots_    = ws+off; off += NB*NC;
  float* bwd_     = ws+off; off += NB*NR*NC;
  float* facc_    = ws+off; off += NB*NR*NC;
  float* rlog_    = ws+off; off += NB*NR*NC;
  int*   bar_     = (int*)(ws+off); off += 2048;
  size_t zero_floats = off;                                // ~3.64M floats = 14.6 MB

  static const size_t SH_BYTES = (size_t)SH_FLOATS*sizeof(float);  // 153,344 B
  hipFuncSetAttribute((const void*)k_persist,
                      hipFuncAttributeMaxDynamicSharedMemorySize, (int)SH_BYTES);

  k_zero<<<256,256,0,stream>>>(ws, zero_floats);
  k_persist<<<NBLK,THR,SH_BYTES,stream>>>(Wx,Wh,b_lstm,Wc,bc,Wo,bo,Wr,br,in_data,
                                          mem_,linkT_,racc_rot,h_rot,ctrl_rot,
                                          dots_,bwd_,facc_,rlog_,out,bar_);
}

// Round 20
// 2807.122 us; speedup vs baseline: 1.1223x; 1.0710x over previous
//
#include <hip/hip_runtime.h>
#include <math.h>

#define NT   64
#define NB   16
#define OUTS 256
#define WL   128
#define NC   256
#define NR   4
#define HIDN 512
#define G4   2048
#define KTOT 1280
#define WCH  391
#define COUT 927
#define EPSF 1e-6f
#define NBLK 256
#define THR  512

// LDS float offsets (weight rows padded off power-of-2 strides)
#define O_WG    0        // 10272: gates W [c][1284]
#define O_WCc   10272    // 2064 : ctrl W [cl][516]
#define O_WOc   12336    // 1024 : out W [k2]
#define O_PRD   13360    // 1024
#define O_USG   14384    // 256
#define O_PRC   14640    // 256
#define O_WDP   14896    // 256
#define O_COWN  15152    // 32
#define O_RED   15184    // 2560
#define O_SCAL  17744    // 32
#define O_SCT   17776    // 16
#define O_UNI   17792    // 20544 union: act[16][1284] | C/D/E scratch
#define SH_FLOATS 38336  // 153,344 B

__device__ __forceinline__ float sigf(float x){ return 1.0f/(1.0f+expf(-x)); }
__device__ __forceinline__ float oneplusf(float x){ return fmaxf(x,0.0f)+log1pf(expf(-fabsf(x)))+1.0f; }

__device__ __forceinline__ float waveSum(float v){
#pragma unroll
  for(int o=32;o>0;o>>=1) v += __shfl_down(v,o,64);
  return v;
}
__device__ __forceinline__ float waveMax(float v){
#pragma unroll
  for(int o=32;o>0;o>>=1) v = fmaxf(v,__shfl_down(v,o,64));
  return v;
}

__device__ __forceinline__ void g_storef(float* p, float v){
  __hip_atomic_store(p, v, __ATOMIC_RELAXED, __HIP_MEMORY_SCOPE_AGENT);
}
__device__ __forceinline__ float2 g_loadf2(const float* p){
  unsigned long long v = __hip_atomic_load((const unsigned long long*)p, __ATOMIC_RELAXED, __HIP_MEMORY_SCOPE_AGENT);
  union{unsigned long long u; float2 f;} c; c.u=v; return c.f;
}

// hierarchical barriers (validated R15/R16 — best of three protocols)
__device__ __forceinline__ void gbarH(int* bar, int b, int gp){
  __syncthreads();
  if (threadIdx.x == 0){
    asm volatile("s_waitcnt vmcnt(0) lgkmcnt(0)" ::: "memory");
    int prev = __hip_atomic_fetch_add(bar + b*32, 1, __ATOMIC_RELAXED, __HIP_MEMORY_SCOPE_AGENT);
    if (prev == 16*gp - 1){
      int p2 = __hip_atomic_fetch_add(bar + 1536, 1, __ATOMIC_RELAXED, __HIP_MEMORY_SCOPE_AGENT);
      if (p2 == 16*gp - 1)
        __hip_atomic_store(bar + 1568, gp, __ATOMIC_RELAXED, __HIP_MEMORY_SCOPE_AGENT);
    }
    while (__hip_atomic_load(bar + 1568, __ATOMIC_RELAXED, __HIP_MEMORY_SCOPE_AGENT) < gp)
      __builtin_amdgcn_s_sleep(1);
    asm volatile("" ::: "memory");
  }
  __syncthreads();
}
__device__ __forceinline__ void lbar(int* bar, int b, int lp){
  __syncthreads();
  if (threadIdx.x == 0){
    asm volatile("s_waitcnt vmcnt(0) lgkmcnt(0)" ::: "memory");
    int prev = __hip_atomic_fetch_add(bar + 512 + b*32, 1, __ATOMIC_RELAXED, __HIP_MEMORY_SCOPE_AGENT);
    if (prev == 16*lp - 1){
      __hip_atomic_store(bar + 1024 + b*32, lp, __ATOMIC_RELAXED, __HIP_MEMORY_SCOPE_AGENT);
    } else {
      while (__hip_atomic_load(bar + 1024 + b*32, __ATOMIC_RELAXED, __HIP_MEMORY_SCOPE_AGENT) < lp)
        __builtin_amdgcn_s_sleep(1);
    }
    asm volatile("" ::: "memory");
  }
  __syncthreads();
}

__global__ void k_zero(float* p, size_t n){
  size_t i = (size_t)blockIdx.x*blockDim.x + threadIdx.x;
  size_t st = (size_t)gridDim.x*blockDim.x;
  for(; i<n; i+=st) p[i]=0.0f;
}

__global__ __launch_bounds__(THR,1) void k_persist(
    const float* __restrict__ Wx, const float* __restrict__ Wh, const float* __restrict__ b_lstm,
    const float* __restrict__ Wc, const float* __restrict__ bc,
    const float* __restrict__ Wo, const float* __restrict__ bo,
    const float* __restrict__ Wr, const float* __restrict__ br,
    const float* __restrict__ in_data,
    float* mem_g, float* linkT_g, float* racc_rot, float* h_rot, float* ctrl_rot,
    float* dots_g, float* bwd_g, float* facc_g, float* rlog_g,
    float* out_g, int* bar)
{
  extern __shared__ float SH[];
  float* s_wg   = SH + O_WG;
  float* s_wc   = SH + O_WCc;
  float* s_wo   = SH + O_WOc;
  float* s_prd  = SH + O_PRD;
  float* s_usage= SH + O_USG;
  float* s_prec = SH + O_PRC;
  float* s_wdp  = SH + O_WDP;
  float* s_cown = SH + O_COWN;
  float* s_red  = SH + O_RED;
  float* s_scal = SH + O_SCAL;
  float* s_sct  = SH + O_SCT;
  float* s_act  = SH + O_UNI;            // [16][1284]
  float* s_ctrl = SH + O_UNI;
  float* s_psi  = SH + O_UNI + 928;
  float* s_su   = SH + O_UNI + 1184;
  float* s_shift= SH + O_UNI + 1440;
  float* s_er   = SH + O_UNI + 1696;
  float* s_mn   = SH + O_UNI + 1824;
  float* s_preo = SH + O_UNI + 1840;
  float* s_link = SH + O_UNI + 1856;     // 4096
  float* s_mem  = SH + O_UNI + 5952;     // 2048
  float* s_fwd  = SH + O_UNI + 8000;     // 1024
  float* s_bwd  = SH + O_UNI + 9024;     // 1024
  float* s_rkey = SH + O_UNI + 10048;    // 528 aligned read-key copy

  const int tid = threadIdx.x, bk = blockIdx.x;
  const int s = bk & 15, b = bk >> 4;

  // ---- one-time LDS weight loads (padded rows: conflict-free) ----
  for(int i=tid;i<10240;i+=THR){
    int c=i&7, k=i>>3;
    int col=(c>>1)*512 + 2*bk + (c&1);
    s_wg[c*1284+k] = (k<768) ? Wx[(size_t)k*G4+col] : Wh[(size_t)(k-768)*G4+col];
  }
  for(int i=tid;i<2048;i+=THR){
    int cl=i&3, k=i>>2;
    int j=4*bk+cl;
    s_wc[cl*516+k] = (bk<232 && j<COUT) ? Wc[(size_t)k*COUT+j] : 0.f;
  }
  for(int i=tid;i<1024;i+=THR){
    s_wo[i] = (i<512) ? Wr[(size_t)i*OUTS+bk] : Wo[(size_t)(i-512)*OUTS+bk];
  }
  for(int i=tid;i<1024;i+=THR) s_prd[i]=0.f;
  for(int i=tid;i<256;i+=THR){ s_usage[i]=0.f; s_prec[i]=0.f; s_wdp[i]=0.f; }
  if(tid<32) s_cown[tid]=0.f;
  __syncthreads();

  int myrk=0; float allocv=0.f;

  for(int t=0;t<=NT;t++){
    // ============ PHASE A: stage act, gates GEMM, LSTM, out(t-1), zero facc ============
    if(t<NT){
      for(int i=tid;i<2048;i+=THR){
        int bi=i>>7, k2=(i&127)*2;
        float2 v = *(const float2*)(in_data + (size_t)t*4096 + bi*256 + k2);
        s_act[bi*1284+k2]=v.x; s_act[bi*1284+k2+1]=v.y;
      }
    }
    for(int i=tid;i<4096;i+=THR){
      int bi=i>>8, k2=(i&255)*2;
      float2 v = *(const float2*)(racc_rot + (size_t)t*8192 + bi*512 + k2);
      s_act[bi*1284+256+k2]=v.x; s_act[bi*1284+256+k2+1]=v.y;
    }
    for(int i=tid;i<4096;i+=THR){
      int bi=i>>8, k2=(i&255)*2;
      float2 v = *(const float2*)(h_rot + (size_t)t*8192 + bi*512 + k2);
      s_act[bi*1284+768+k2]=v.x; s_act[bi*1284+768+k2+1]=v.y;
    }
    if(tid<64) g_storef(facc_g + b*1024 + s*64 + tid, 0.0f);
    __syncthreads();
    if(t<NT){
      int oc=tid&127, q=tid>>7; int c=oc>>4, bi=oc&15;
      const float* ap = s_act + bi*1284;
      const float* wp = s_wg + c*1284;
      float4 a4={0,0,0,0};
      int k0=q*320;
#pragma unroll 8
      for(int it=0;it<80;it++){
        int k=k0+it*4;
        float4 a=*(const float4*)(ap+k);
        float4 w=*(const float4*)(wp+k);
        a4.x+=a.x*w.x; a4.y+=a.y*w.y; a4.z+=a.z*w.z; a4.w+=a.w*w.w;
      }
      s_red[q*128+oc]=a4.x+a4.y+a4.z+a4.w;
    }
    if(t>0){
      int bi=tid>>5, q=tid&31;
      const float* ap = s_act + bi*1284 + 256;
      float acc=0.f;
#pragma unroll 8
      for(int it=0;it<32;it++){
        int k2=q+it*32;                 // stride-1 per lane: conflict-free
        acc += ap[k2]*s_wo[k2];
      }
      s_red[512 + bi*32 + q] = acc;
    }
    __syncthreads();
    if(t<NT && tid<32){
      int j2=tid>>4, bi=tid&15;
      float g4[4];
#pragma unroll
      for(int g=0;g<4;g++){
        int c=g*2+j2;
        float v = s_red[0*128+c*16+bi]+s_red[1*128+c*16+bi]+s_red[2*128+c*16+bi]+s_red[3*128+c*16+bi];
        v += b_lstm[g*512 + 2*bk + j2];
        g4[g]=v;
      }
      float cc = sigf(g4[1])*s_cown[j2*16+bi] + sigf(g4[0])*tanhf(g4[2]);
      float hh = sigf(g4[3])*tanhf(cc);
      s_cown[j2*16+bi]=cc;
      g_storef(h_rot + (size_t)(t+1)*8192 + bi*512 + 2*bk + j2, hh);
    }
    if(t>0 && tid>=64 && tid<80){
      int bi=tid-64;
      float acc=bo[bk]+br[bk];
#pragma unroll
      for(int q=0;q<32;q++) acc += s_red[512+bi*32+q];
      out_g[((size_t)(t-1)*NB+bi)*OUTS + bk] = acc;
    }
    if(t==NT) break;
    gbarH(bar,b,3*t+1);

    // ============ PHASE B: ctrl GEMM ============
    for(int i=tid;i<4096;i+=THR){
      int bi=i>>8, k2=(i&255)*2;
      float2 v = *(const float2*)(h_rot + (size_t)(t+1)*8192 + bi*512 + k2);
      s_act[bi*1284+768+k2]=v.x; s_act[bi*1284+768+k2+1]=v.y;
    }
    __syncthreads();
    if(bk<232){
      int o=tid&63, ks=tid>>6; int cl=o>>4, bi=o&15;
      int j=4*bk+cl;
      float acc=0.f;
      if(j<COUT){
        const float* ap=s_act+bi*1284+768;
        const float* wp=s_wc+cl*516;
#pragma unroll
        for(int kk=0;kk<16;kk++){
          int k=ks*64+kk*4;
          float4 a=*(const float4*)(ap+k);
          float4 w=*(const float4*)(wp+k);
          acc += a.x*w.x+a.y*w.y+a.z*w.z+a.w*w.w;
        }
      }
      s_red[ks*64+o]=acc;
    }
    __syncthreads();
    if(bk<232 && tid<64){
      int cl=tid>>4, bi=tid&15; int j=4*bk+cl;
      if(j<COUT){
        float a=bc[j];
#pragma unroll
        for(int ks=0;ks<8;ks++) a+=s_red[ks*64+tid];
        g_storef(ctrl_rot + (size_t)t*14848 + bi*928 + j, fminf(fmaxf(a,-20.f),20.f));
      }
    }
    gbarH(bar,b,3*t+2);

    // ============ PHASE C: psi/usage/alloc + write-key dots ============
    for(int i=tid;i<464;i+=THR){
      float2 v = *(const float2*)(ctrl_rot + (size_t)t*14848 + b*928 + 2*i);
      s_ctrl[2*i]=v.x; s_ctrl[2*i+1]=v.y;
    }
    __syncthreads();
    for(int i=tid;i<528;i+=THR) s_rkey[i]=s_ctrl[WCH+i];
    if(tid<256){
      int n=tid;
      float psi=1.f;
#pragma unroll
      for(int r=0;r<NR;r++) psi *= 1.f - sigf(s_ctrl[384+r])*s_prd[r*256+n];
      s_psi[n]=psi;
      float uo=s_usage[n], pw=s_wdp[n];
      s_usage[n]=(uo+pw-uo*pw)*psi;
    } else if(tid<384){
      int w=tid-256; s_er[w]=sigf(s_ctrl[128+w]);
    } else if(tid>=448){
      int l=tid-448;
      float v=s_ctrl[l]*s_ctrl[l]+s_ctrl[l+64]*s_ctrl[l+64];
      v=waveSum(v);
      if(l==0) s_scal[0]=v;
    }
    __syncthreads();
    {
      int n=tid&255, hf=tid>>8;
      float u2=s_usage[n]*(1.f-EPSF)+EPSF; int c=0;
      for(int jj=0;jj<128;jj++){
        int j=hf*128+jj;
        float uj=s_usage[j]*(1.f-EPSF)+EPSF;
        c += (uj<u2)||(uj==u2 && j<n);
      }
      s_red[hf*256+n]=(float)c;
    }
    __syncthreads();
    if(tid<256){
      myrk=(int)(s_red[tid]+s_red[256+tid]);
      s_su[myrk]=s_usage[tid]*(1.f-EPSF)+EPSF;
    }
    __syncthreads();
    if(tid<16){
      float run=1.f;
#pragma unroll
      for(int i=0;i<16;i++){ int idx=tid*16+i; s_shift[idx]=run; run*=s_su[idx]; }
      s_sct[tid]=run;
    }
    __syncthreads();
    if(tid==0){
      float run=1.f;
      for(int j=0;j<16;j++){ float t2=s_sct[j]; s_sct[j]=run; run*=t2; }
    }
    __syncthreads();
    if(tid<256) allocv=(1.f-s_su[myrk])*s_shift[myrk]*s_sct[myrk>>4];
    {
      int nr=tid>>5, wq=tid&31;
      int n=s*16+nr;
      float4 m=((const float4*)(mem_g + ((size_t)(b*256+n))*WL))[wq];
      int w=wq*4;
      float4 kk=*(const float4*)(s_ctrl+w);
      float dt=m.x*kk.x+m.y*kk.y+m.z*kk.z+m.w*kk.w;
      float m2=m.x*m.x+m.y*m.y+m.z*m.z+m.w*m.w;
      s_red[nr*32+wq]=dt; s_red[512+nr*32+wq]=m2;
    }
    __syncthreads();
    if(tid<16){
      float dt=0,m2=0;
#pragma unroll
      for(int q=0;q<32;q++){ dt+=s_red[tid*32+q]; m2+=s_red[512+tid*32+q]; }
      float wb=oneplusf(s_ctrl[388]);
      float lg=dt*wb/(sqrtf(s_scal[0])*sqrtf(m2)+EPSF);
      g_storef(dots_g+b*256+s*16+tid, lg);
    }
    lbar(bar,b,2*t+1);

    // ============ PHASE D ============
    if(tid<128){
      float2 v=g_loadf2(dots_g+b*256+2*tid);
      s_red[2*tid]=v.x; s_red[2*tid+1]=v.y;
    }
    __syncthreads();
    {
      float lv=s_red[tid&255];
      float mv=waveMax(lv);
      if((tid&63)==0) s_scal[8+(tid>>6)]=mv;
      __syncthreads();
      float mx=s_scal[8]; for(int i=9;i<16;i++) mx=fmaxf(mx,s_scal[i]);
      float ex=expf(lv-mx);
      float sv=waveSum(ex);
      __syncthreads();
      if((tid&63)==0) s_scal[8+(tid>>6)]=sv;
      __syncthreads();
      float se=0; for(int i=8;i<16;i++) se+=s_scal[i]; se*=0.5f;
      if(tid<256){
        float cw=ex/se;
        float ag=sigf(s_ctrl[389]), wg=sigf(s_ctrl[390]);
        s_wdp[tid]=wg*(ag*allocv+(1.f-ag)*cw);
      }
    }
    __syncthreads();
    {
      float wv=waveSum(s_wdp[tid&255]);
      if((tid&63)==0) s_scal[8+(tid>>6)]=wv;
      __syncthreads();
      float swd=0; for(int i=8;i<16;i++) swd+=s_scal[i]; swd*=0.5f;
      if(tid<16) s_preo[tid]=s_prec[s*16+tid];
      __syncthreads();
      if(tid<256) s_prec[tid]=(1.f-swd)*s_prec[tid]+s_wdp[tid];
    }
    __syncthreads();
    {
      int nr=tid>>5, ic=tid&31;
      int n=s*16+nr;
      float wdn=s_wdp[n], pre=s_preo[nr];
      float4* lp=(float4*)(linkT_g+((size_t)(b*256+n))*256);
#pragma unroll
      for(int h2=0;h2<2;h2++){
        int i4=h2*32+ic;
        float4 l=lp[i4];
        int i0=i4*4;
        float4 wv=*(float4*)&s_wdp[i0];
        float4 nl;
        nl.x=(i0  ==n)?0.f:((1.f-wv.x-wdn)*l.x+wv.x*pre);
        nl.y=(i0+1==n)?0.f:((1.f-wv.y-wdn)*l.y+wv.y*pre);
        nl.z=(i0+2==n)?0.f:((1.f-wv.z-wdn)*l.z+wv.z*pre);
        nl.w=(i0+3==n)?0.f:((1.f-wv.w-wdn)*l.w+wv.w*pre);
        lp[i4]=nl;
        *(float4*)&s_link[nr*256+i0]=nl;
      }
    }
    __syncthreads();
    {   // bwd (owned n, i = q*32+ic : bank-conflict-free)
      int nr=tid>>5, ic=tid&31;
      float b0=0,b1=0,b2=0,b3=0;
#pragma unroll
      for(int q=0;q<8;q++){
        int i=q*32+ic;
        float l=s_link[nr*256+i];
        b0+=l*s_prd[i]; b1+=l*s_prd[256+i]; b2+=l*s_prd[512+i]; b3+=l*s_prd[768+i];
      }
      s_red[(0*16+nr)*32+ic]=b0; s_red[(1*16+nr)*32+ic]=b1;
      s_red[(2*16+nr)*32+ic]=b2; s_red[(3*16+nr)*32+ic]=b3;
    }
    __syncthreads();
    if(tid<64){
      int r=tid>>4, nr=tid&15;
      float a=0;
#pragma unroll
      for(int q=0;q<32;q++) a+=s_red[(r*16+nr)*32+q];
      g_storef(bwd_g + b*1024 + r*256 + s*16+nr, a);
    }
    {
      int np=tid&255, dh=tid>>8;
      float f0=0,f1=0;
#pragma unroll
      for(int jr=0;jr<16;jr++){
        float l=s_link[jr*256+np];
        int j=s*16+jr;
        f0+=l*s_prd[(2*dh)*256+j];
        f1+=l*s_prd[(2*dh+1)*256+j];
      }
      atomicAdd(facc_g + b*1024 + (2*dh)*256 + np, f0);
      atomicAdd(facc_g + b*1024 + (2*dh+1)*256 + np, f1);
    }
    {
      int nr=tid>>5, wq=tid&31;
      int n=s*16+nr;
      float ps=s_psi[n], wdn=s_wdp[n];
      float4* mr=(float4*)(mem_g+((size_t)(b*256+n))*WL);
      float4 m=mr[wq]; int w=wq*4;
      float4 er=*(const float4*)(s_er+w);
      float4 wv=*(const float4*)(s_ctrl+256+w);
      m.x=m.x*ps*(1.f-wdn*er.x)+wdn*wv.x;
      m.y=m.y*ps*(1.f-wdn*er.y)+wdn*wv.y;
      m.z=m.z*ps*(1.f-wdn*er.z)+wdn*wv.z;
      m.w=m.w*ps*(1.f-wdn*er.w)+wdn*wv.w;
      mr[wq]=m;
      *(float4*)&s_mem[nr*128+w]=m;
    }
    __syncthreads();
    {
      int nr=tid>>5, wq=tid&31;
      float4 m=*(float4*)&s_mem[nr*128+wq*4];
      int w=wq*4;
      float4 k0=*(const float4*)(s_rkey+w);
      float4 k1=*(const float4*)(s_rkey+132+w);
      float4 k2=*(const float4*)(s_rkey+264+w);
      float4 k3=*(const float4*)(s_rkey+396+w);
      float d0=m.x*k0.x+m.y*k0.y+m.z*k0.z+m.w*k0.w;
      float d1=m.x*k1.x+m.y*k1.y+m.z*k1.z+m.w*k1.w;
      float d2=m.x*k2.x+m.y*k2.y+m.z*k2.z+m.w*k2.w;
      float d3=m.x*k3.x+m.y*k3.y+m.z*k3.z+m.w*k3.w;
      float m2=m.x*m.x+m.y*m.y+m.z*m.z+m.w*m.w;
      s_red[(0*16+nr)*32+wq]=d0; s_red[(1*16+nr)*32+wq]=d1;
      s_red[(2*16+nr)*32+wq]=d2; s_red[(3*16+nr)*32+wq]=d3;
      s_red[2048+nr*32+wq]=m2;
    }
    if(tid<256){
      int r=tid>>6, l=tid&63;
      const float* kk=s_rkey+r*132;
      float kv=kk[l]*kk[l]+kk[l+64]*kk[l+64];
      kv=waveSum(kv);
      if(l==0) s_scal[4+r]=sqrtf(kv);
    }
    __syncthreads();
    if(tid<16){
      float m2=0;
#pragma unroll
      for(int q=0;q<32;q++) m2+=s_red[2048+tid*32+q];
      s_mn[tid]=sqrtf(m2);
    }
    __syncthreads();
    if(tid<64){
      int r=tid>>4, nr=tid&15;
      float dt=0;
#pragma unroll
      for(int q=0;q<32;q++) dt+=s_red[(r*16+nr)*32+q];
      float rb=oneplusf(s_rkey[r*132+128]);
      float lg=dt*rb/(s_scal[4+r]*s_mn[nr]+EPSF);
      g_storef(rlog_g+b*1024+r*256+s*16+nr,lg);
    }
    lbar(bar,b,2*t+2);

    // ============ PHASE E ============
    {
      float2 v=g_loadf2(facc_g + b*1024 + 2*tid);
      s_fwd[2*tid]=v.x; s_fwd[2*tid+1]=v.y;
    }
    {
      float2 v=g_loadf2(bwd_g+b*1024+2*tid);
      s_bwd[2*tid]=v.x; s_bwd[2*tid+1]=v.y;
    }
    {
      float2 v=g_loadf2(rlog_g+b*1024+2*tid);
      s_red[2*tid]=v.x; s_red[2*tid+1]=v.y;
    }
    __syncthreads();
    {
      int l=tid&63, w=tid>>6;
      float* rp=(w<4)? (s_fwd+w*256) : (s_bwd+(w-4)*256);
      float a=rp[l]+EPSF, b2=rp[l+64]+EPSF, c2=rp[l+128]+EPSF, d2=rp[l+192]+EPSF;
      float mxr=waveMax(fmaxf(fmaxf(a,b2),fmaxf(c2,d2)));
      mxr=__shfl(mxr,0,64);
      float ff=oneplusf(s_ctrl[919+w]);
      a=powf(a/mxr,ff); b2=powf(b2/mxr,ff); c2=powf(c2/mxr,ff); d2=powf(d2/mxr,ff);
      float sm=waveSum(a+b2+c2+d2);
      sm=__shfl(sm,0,64);
      float inv=1.f/sm;
      rp[l]=a*inv; rp[l+64]=b2*inv; rp[l+128]=c2*inv; rp[l+192]=d2*inv;
    }
    {
      int l=tid&63, w=tid>>6, row=w&3;
      float* rr=s_red+row*256;
      float a=rr[l],b2=rr[l+64],c2=rr[l+128],d2=rr[l+192];
      float mx2=waveMax(fmaxf(fmaxf(a,b2),fmaxf(c2,d2)));
      mx2=__shfl(mx2,0,64);
      a=expf(a-mx2); b2=expf(b2-mx2); c2=expf(c2-mx2); d2=expf(d2-mx2);
      float sm=waveSum(a+b2+c2+d2);
      sm=__shfl(sm,0,64);
      float inv=1.f/sm;
      rr[l]=a*inv; rr[l+64]=b2*inv; rr[l+128]=c2*inv; rr[l+192]=d2*inv;
    }
    __syncthreads();
    if(tid<256){
      int n=tid;
#pragma unroll
      for(int r=0;r<NR;r++){
        float cr=s_red[r*256+n];
        float fw=s_fwd[r*256+n];
        float bw=s_bwd[r*256+n];
        int mo=WCH+r*132+129;
        float m0=s_ctrl[mo],m1=s_ctrl[mo+1],m2s=s_ctrl[mo+2];
        float mm=fmaxf(m0,fmaxf(m1,m2s));
        float e0=expf(m0-mm),e1=expf(m1-mm),e2=expf(m2s-mm);
        float es=e0+e1+e2;
        s_prd[r*256+n]=(e0*bw+e1*cr+e2*fw)/es;
      }
    }
    __syncthreads();
    {
      int w=tid&127, nq=tid>>7;
      float a0=0,a1=0,a2=0,a3=0;
#pragma unroll
      for(int q=0;q<4;q++){
        int nr=nq*4+q; int n=s*16+nr;
        float mv=s_mem[nr*128+w];
        a0+=s_prd[n]*mv; a1+=s_prd[256+n]*mv; a2+=s_prd[512+n]*mv; a3+=s_prd[768+n]*mv;
      }
      s_red[(0*4+nq)*128+w]=a0; s_red[(1*4+nq)*128+w]=a1;
      s_red[(2*4+nq)*128+w]=a2; s_red[(3*4+nq)*128+w]=a3;
    }
    __syncthreads();
    {
      int r=tid>>7, w=tid&127;
      float rd=s_red[(r*4+0)*128+w]+s_red[(r*4+1)*128+w]+s_red[(r*4+2)*128+w]+s_red[(r*4+3)*128+w];
      atomicAdd(racc_rot + (size_t)(t+1)*8192 + b*512 + r*128 + w, rd);
    }
    gbarH(bar,b,3*t+3);
  }
}

extern "C" void kernel_launch(void* const* d_in, const int* in_sizes, int n_in,
                              void* d_out, int out_size, void* d_ws, size_t ws_size,
                              hipStream_t stream) {
  const float* in_data = (const float*)d_in[0];
  const float* Wx      = (const float*)d_in[1];
  const float* Wh      = (const float*)d_in[2];
  const float* b_lstm  = (const float*)d_in[3];
  const float* Wc      = (const float*)d_in[4];
  const float* bc      = (const float*)d_in[5];
  const float* Wo      = (const float*)d_in[6];
  const float* bo      = (const float*)d_in[7];
  const float* Wr      = (const float*)d_in[8];
  const float* br      = (const float*)d_in[9];
  float* out = (float*)d_out;
  float* ws  = (float*)d_ws;

  size_t off=0;
  float* mem_     = ws+off; off += (size_t)NB*NC*WL;       // 524288
  float* linkT_   = ws+off; off += (size_t)NB*NC*NC;       // 1048576
  float* racc_rot = ws+off; off += (size_t)65*8192;        // 532480
  float* h_rot    = ws+off; off += (size_t)65*8192;        // 532480
  float* ctrl_rot = ws+off; off += (size_t)64*14848;       // 950272
  float* dots_    = ws+off; off += NB*NC;
  float* bwd_     = ws+off; off += NB*NR*NC;
  float* facc_    = ws+off; off += NB*NR*NC;
  float* rlog_    = ws+off; off += NB*NR*NC;
  int*   bar_     = (int*)(ws+off); off += 2048;
  size_t zero_floats = off;                                // ~3.64M floats = 14.6 MB

  static const size_t SH_BYTES = (size_t)SH_FLOATS*sizeof(float);  // 153,344 B
  hipFuncSetAttribute((const void*)k_persist,
                      hipFuncAttributeMaxDynamicSharedMemorySize, (int)SH_BYTES);

  k_zero<<<256,256,0,stream>>>(ws, zero_floats);
  k_persist<<<NBLK,THR,SH_BYTES,stream>>>(Wx,Wh,b_lstm,Wc,bc,Wo,bo,Wr,br,in_data,
                                          mem_,linkT_,racc_rot,h_rot,ctrl_rot,
                                          dots_,bwd_,facc_,rlog_,out,bar_);
}